// Round 1
// baseline (804.043 us; speedup 1.0000x reference)
//
#include <hip/hip_runtime.h>

// CombPool2d: x (16,192,224,224) f32, w_avg/w_max (1,192,1,1) f32.
// out = w_avg^2 * avgpool2x2s2(x) + w_max^2 * maxpool2x2s2(x)  -> (16,192,112,112)
//
// Memory-bound: 616.6 MB read + 154.1 MB write, ~8 flops/out elem.
// One thread per 2 output pixels: 2x float4 loads (aligned: row stride 896 B,
// col offset 16*ow2 B) + 1x float2 store. Fully coalesced at 16 B/lane.

#define IN_HW   (224 * 224)
#define OUT_HW  (112 * 112)
#define NCH     192

__global__ __launch_bounds__(256) void combpool2d_kernel(
    const float* __restrict__ x,
    const float* __restrict__ w_avg,
    const float* __restrict__ w_max,
    float* __restrict__ out,
    int n2)  // number of output *pairs* = out_size / 2
{
    int i = blockIdx.x * blockDim.x + threadIdx.x;
    if (i >= n2) return;

    // decompose: i -> (bc, oh, ow2) with ow2 in [0,56), oh in [0,112)
    int ow2 = i % 56;          // pair index along output width (112/2)
    int t   = i / 56;
    int oh  = t % 112;
    int bc  = t / 112;         // fused batch*channel index
    int c   = bc % NCH;

    const float* row0 = x + (size_t)bc * IN_HW + (size_t)(2 * oh) * 224;
    float4 a = ((const float4*)row0)[ow2];            // input row 2*oh,   cols 4*ow2..+3
    float4 b = ((const float4*)(row0 + 224))[ow2];    // input row 2*oh+1, cols 4*ow2..+3

    float ca = w_avg[c]; ca *= ca;
    float cm = w_max[c]; cm *= cm;

    float avg0 = 0.25f * ((a.x + a.y) + (b.x + b.y));
    float mx0  = fmaxf(fmaxf(a.x, a.y), fmaxf(b.x, b.y));
    float avg1 = 0.25f * ((a.z + a.w) + (b.z + b.w));
    float mx1  = fmaxf(fmaxf(a.z, a.w), fmaxf(b.z, b.w));

    float2 o;
    o.x = ca * avg0 + cm * mx0;
    o.y = ca * avg1 + cm * mx1;

    float* orow = out + (size_t)bc * OUT_HW + (size_t)oh * 112;
    ((float2*)orow)[ow2] = o;
}

extern "C" void kernel_launch(void* const* d_in, const int* in_sizes, int n_in,
                              void* d_out, int out_size, void* d_ws, size_t ws_size,
                              hipStream_t stream) {
    const float* x     = (const float*)d_in[0];
    const float* w_avg = (const float*)d_in[1];
    const float* w_max = (const float*)d_in[2];
    float* out = (float*)d_out;

    int n2 = out_size / 2;                 // 19,267,584 thread work-items
    int block = 256;
    int grid = (n2 + block - 1) / block;
    combpool2d_kernel<<<grid, block, 0, stream>>>(x, w_avg, w_max, out, n2);
}